// Round 7
// baseline (215.886 us; speedup 1.0000x reference)
//
#include <hip/hip_runtime.h>

// ClusterDiceLoss: segmented dice over 64 clusters of a 256^3 volume.
// History: R1 115us grid-stride; R2 432us channel-aliased batch; R3 76us
// contiguous+x4 unroll; R4 128us scratch spill (but: 3.1 TB/s path proven);
// R5 85us lane-privatized LDS (conflicts->0, slower); R6 74us atomic-free
// epilogue (global-atomic tail ~3us only).
// R6 analysis: fixed ~56us volume-independent cost (warm 1MB replay == cold
// 100MB pass == 74us). Theory: 2048 2-iteration blocks never reach steady
// state; per-block startup dominates. R7: 1024 blocks x 4 deep iterations.

#define NSEG 65          // clusters 0..64 (0 = background, dropped)
#define NBLK 1024
#define THREADS 256
#define NWAVES 4

// Pack per-element contribution into one u64: inter<<42 | sum_p<<21 | sum_t.
// Global per-segment field totals ~260k << 2^21, so fields never carry.
__device__ __forceinline__ unsigned long long pack_contrib(float p, float t) {
    unsigned long long sp = (p != 0.0f) ? 1ull : 0ull;
    unsigned long long st = (t != 0.0f) ? 1ull : 0ull;
    return ((sp & st) << 42) | (sp << 21) | st;
}

__device__ __forceinline__ void accum4(unsigned long long (*s_cnt)[NSEG], int wave,
                                       float4 p, float4 t, int4 l) {
    atomicAdd(&s_cnt[wave][l.x], pack_contrib(p.x, t.x));
    atomicAdd(&s_cnt[wave][l.y], pack_contrib(p.y, t.y));
    atomicAdd(&s_cnt[wave][l.z], pack_contrib(p.z, t.z));
    atomicAdd(&s_cnt[wave][l.w], pack_contrib(p.w, t.w));
}

__global__ __launch_bounds__(THREADS) void seg_count_kernel(
    const float* __restrict__ pred,
    const float* __restrict__ target,
    const int* __restrict__ labels,
    unsigned long long* __restrict__ g_part,   // [NBLK][64] partials (ws)
    int n)
{
    __shared__ unsigned long long s_cnt[NWAVES][NSEG];
    const int tid = threadIdx.x;
    const int wave = tid >> 6;

    for (int i = tid; i < NWAVES * NSEG; i += THREADS)
        ((unsigned long long*)s_cnt)[i] = 0ull;
    __syncthreads();

    const int n_vec = n >> 2;  // float4 groups
    const float4* __restrict__ p4 = (const float4*)pred;
    const float4* __restrict__ t4 = (const float4*)target;
    const int4*   __restrict__ l4 = (const int4*)labels;

    // contiguous chunk per block; 4x deeper loop than R6 (4 iters/thread)
    const int chunk = (n_vec + (int)gridDim.x - 1) / (int)gridDim.x;
    const int base = blockIdx.x * chunk;
    const int end = min(base + chunk, n_vec);

    int idx = base + tid;
    for (; idx + 3 * THREADS < end; idx += 4 * THREADS) {
        float4 p0 = p4[idx];
        float4 p1 = p4[idx + THREADS];
        float4 p2 = p4[idx + 2 * THREADS];
        float4 p3 = p4[idx + 3 * THREADS];
        float4 t0 = t4[idx];
        float4 t1 = t4[idx + THREADS];
        float4 t2 = t4[idx + 2 * THREADS];
        float4 t3 = t4[idx + 3 * THREADS];
        int4   l0 = l4[idx];
        int4   l1 = l4[idx + THREADS];
        int4   l2 = l4[idx + 2 * THREADS];
        int4   l3 = l4[idx + 3 * THREADS];
        accum4(s_cnt, wave, p0, t0, l0);
        accum4(s_cnt, wave, p1, t1, l1);
        accum4(s_cnt, wave, p2, t2, l2);
        accum4(s_cnt, wave, p3, t3, l3);
    }
    for (; idx < end; idx += THREADS)
        accum4(s_cnt, wave, p4[idx], t4[idx], l4[idx]);

    // scalar tail (n not divisible by 4): block 0 only (dead for n=2^24)
    if (blockIdx.x == 0) {
        for (int i = ((n >> 2) << 2) + tid; i < n; i += THREADS)
            atomicAdd(&s_cnt[wave][labels[i]], pack_contrib(pred[i], target[i]));
    }
    __syncthreads();

    // atomic-free epilogue: fold wave copies, store 64 packed partials
    // contiguously (coalesced 512 B per block). Segment 0 dropped here.
    for (int s = tid; s < NSEG; s += THREADS) {
        unsigned long long tot = 0;
        #pragma unroll
        for (int w = 0; w < NWAVES; ++w) tot += s_cnt[w][s];
        if (s >= 1)
            g_part[(unsigned)blockIdx.x * 64u + (unsigned)(s - 1)] = tot;
    }
}

// One block, 1024 threads: reduce [NBLK][64] partials -> 64 dice -> scalar.
__global__ __launch_bounds__(1024) void reduce_finalize_kernel(
    const unsigned long long* __restrict__ g_part,
    const int* __restrict__ nc_ptr,
    float* __restrict__ out)
{
    __shared__ unsigned long long s_part[16][64];   // 8 KB
    const int tid = threadIdx.x;
    const int seg = tid & 63;      // 0..63 -> cluster seg+1
    const int j = tid >> 6;        // 0..15, each covers NBLK/16 blocks

    unsigned long long acc = 0;
    const int bpj = NBLK / 16;
    for (int b = j * bpj; b < (j + 1) * bpj; ++b)
        acc += g_part[(unsigned)b * 64u + (unsigned)seg];
    s_part[j][seg] = acc;
    __syncthreads();

    if (tid < 64) {
        unsigned long long tot = 0;
        #pragma unroll
        for (int jj = 0; jj < 16; ++jj) tot += s_part[jj][seg];
        float in = (float)(tot >> 42);
        float sp = (float)((tot >> 21) & 0x1FFFFFull);
        float st = (float)(tot & 0x1FFFFFull);
        float uni = sp + st;
        float local = (uni > 0.0f) ? (2.0f * in / uni) : 1.0f;
        #pragma unroll
        for (int off = 32; off > 0; off >>= 1)
            local += __shfl_down(local, off);
        if (tid == 0) out[0] = 1.0f - local / (float)(*nc_ptr);
    }
}

extern "C" void kernel_launch(void* const* d_in, const int* in_sizes, int n_in,
                              void* d_out, int out_size, void* d_ws, size_t ws_size,
                              hipStream_t stream) {
    const float* pred   = (const float*)d_in[0];
    const float* target = (const float*)d_in[1];
    const int*   labels = (const int*)d_in[2];
    const int*   nc_ptr = (const int*)d_in[3];
    float* out = (float*)d_out;
    unsigned long long* g_part = (unsigned long long*)d_ws;  // 512 KB, fully overwritten

    const int n = in_sizes[0];

    seg_count_kernel<<<NBLK, THREADS, 0, stream>>>(
        pred, target, labels, g_part, n);
    reduce_finalize_kernel<<<1, 1024, 0, stream>>>(g_part, nc_ptr, out);
}

// Round 8
// 209.566 us; speedup vs baseline: 1.0302x; 1.0302x over previous
//
#include <hip/hip_runtime.h>

// ClusterDiceLoss: segmented dice over 64 clusters of a 256^3 volume.
// History: R1 115us; R2 432us (channel alias); R3 76us (contig+x4);
// R4 128us (scratch spill, 3.1TB/s path proven); R5 85us (lane-private LDS,
// conflicts->0, slower); R6 74us (atomic-free epilogue); R7 75us (1024 blocks
// — per-block-overhead theory falsified).
// Standing theory: compiler sinks batched loads (VGPR=36 < 48 needed for 12
// in-flight dwordx4) -> ~3 loads in flight, per-wave period ~latency-bound.
// R8: ONE mega-iteration per block: 24 named loads (96 VGPR), then
// sched_barrier(0) to forbid sinking, then all 32 consumes. One vmcnt wait
// per wave. launch_bounds(256,4) -> VGPR cap 128.

#define NSEG 65          // clusters 0..64 (0 = background, dropped)
#define NBLK 2048
#define THREADS 256
#define NWAVES 4

// Pack per-element contribution into one u64: inter<<42 | sum_p<<21 | sum_t.
// Global per-segment field totals ~260k << 2^21, so fields never carry.
__device__ __forceinline__ unsigned long long pack_contrib(float p, float t) {
    unsigned long long sp = (p != 0.0f) ? 1ull : 0ull;
    unsigned long long st = (t != 0.0f) ? 1ull : 0ull;
    return ((sp & st) << 42) | (sp << 21) | st;
}

__device__ __forceinline__ void accum4(unsigned long long (*s_cnt)[NSEG], int wave,
                                       float4 p, float4 t, int4 l) {
    atomicAdd(&s_cnt[wave][l.x], pack_contrib(p.x, t.x));
    atomicAdd(&s_cnt[wave][l.y], pack_contrib(p.y, t.y));
    atomicAdd(&s_cnt[wave][l.z], pack_contrib(p.z, t.z));
    atomicAdd(&s_cnt[wave][l.w], pack_contrib(p.w, t.w));
}

__global__ __launch_bounds__(THREADS, 4) void seg_count_kernel(
    const float* __restrict__ pred,
    const float* __restrict__ target,
    const int* __restrict__ labels,
    unsigned long long* __restrict__ g_part,   // [NBLK][64] partials (ws)
    int n)
{
    __shared__ unsigned long long s_cnt[NWAVES][NSEG];
    const int tid = threadIdx.x;
    const int wave = tid >> 6;

    for (int i = tid; i < NWAVES * NSEG; i += THREADS)
        ((unsigned long long*)s_cnt)[i] = 0ull;
    __syncthreads();

    const int n_vec = n >> 2;  // float4 groups
    const float4* __restrict__ p4 = (const float4*)pred;
    const float4* __restrict__ t4 = (const float4*)target;
    const int4*   __restrict__ l4 = (const int4*)labels;

    const int chunk = (n_vec + (int)gridDim.x - 1) / (int)gridDim.x;
    const int base = blockIdx.x * chunk;
    const int end = min(base + chunk, n_vec);

    int idx = base + tid;
    // Mega-iteration: 8 groups = 24 named loads held live (96 VGPRs), then a
    // hard scheduling fence, then all consumes. For n=2^24 this runs exactly
    // once per block (chunk = 2048 = 8*THREADS).
    for (; idx + 7 * THREADS < end; idx += 8 * THREADS) {
        float4 p0 = p4[idx];
        float4 p1 = p4[idx + THREADS];
        float4 p2 = p4[idx + 2 * THREADS];
        float4 p3 = p4[idx + 3 * THREADS];
        float4 p4v = p4[idx + 4 * THREADS];
        float4 p5 = p4[idx + 5 * THREADS];
        float4 p6 = p4[idx + 6 * THREADS];
        float4 p7 = p4[idx + 7 * THREADS];
        float4 t0 = t4[idx];
        float4 t1 = t4[idx + THREADS];
        float4 t2 = t4[idx + 2 * THREADS];
        float4 t3 = t4[idx + 3 * THREADS];
        float4 t4v = t4[idx + 4 * THREADS];
        float4 t5 = t4[idx + 5 * THREADS];
        float4 t6 = t4[idx + 6 * THREADS];
        float4 t7 = t4[idx + 7 * THREADS];
        int4   l0 = l4[idx];
        int4   l1 = l4[idx + THREADS];
        int4   l2 = l4[idx + 2 * THREADS];
        int4   l3 = l4[idx + 3 * THREADS];
        int4   l4v = l4[idx + 4 * THREADS];
        int4   l5 = l4[idx + 5 * THREADS];
        int4   l6 = l4[idx + 6 * THREADS];
        int4   l7 = l4[idx + 7 * THREADS];
        // No instruction may cross this fence: the 24 loads above must all
        // be issued (and their 96 dest VGPRs allocated) before any consume.
        __builtin_amdgcn_sched_barrier(0);
        accum4(s_cnt, wave, p0, t0, l0);
        accum4(s_cnt, wave, p1, t1, l1);
        accum4(s_cnt, wave, p2, t2, l2);
        accum4(s_cnt, wave, p3, t3, l3);
        accum4(s_cnt, wave, p4v, t4v, l4v);
        accum4(s_cnt, wave, p5, t5, l5);
        accum4(s_cnt, wave, p6, t6, l6);
        accum4(s_cnt, wave, p7, t7, l7);
    }
    for (; idx < end; idx += THREADS)
        accum4(s_cnt, wave, p4[idx], t4[idx], l4[idx]);

    // scalar tail (n not divisible by 4): block 0 only (dead for n=2^24)
    if (blockIdx.x == 0) {
        for (int i = ((n >> 2) << 2) + tid; i < n; i += THREADS)
            atomicAdd(&s_cnt[wave][labels[i]], pack_contrib(pred[i], target[i]));
    }
    __syncthreads();

    // atomic-free epilogue: fold wave copies, store 64 packed partials
    // contiguously (coalesced 512 B per block). Segment 0 dropped here.
    for (int s = tid; s < NSEG; s += THREADS) {
        unsigned long long tot = 0;
        #pragma unroll
        for (int w = 0; w < NWAVES; ++w) tot += s_cnt[w][s];
        if (s >= 1)
            g_part[(unsigned)blockIdx.x * 64u + (unsigned)(s - 1)] = tot;
    }
}

// One block, 1024 threads: reduce [NBLK][64] partials -> 64 dice -> scalar.
__global__ __launch_bounds__(1024) void reduce_finalize_kernel(
    const unsigned long long* __restrict__ g_part,
    const int* __restrict__ nc_ptr,
    float* __restrict__ out)
{
    __shared__ unsigned long long s_part[16][64];   // 8 KB
    const int tid = threadIdx.x;
    const int seg = tid & 63;      // 0..63 -> cluster seg+1
    const int j = tid >> 6;        // 0..15, each covers NBLK/16 blocks

    unsigned long long acc = 0;
    const int bpj = NBLK / 16;
    for (int b = j * bpj; b < (j + 1) * bpj; ++b)
        acc += g_part[(unsigned)b * 64u + (unsigned)seg];
    s_part[j][seg] = acc;
    __syncthreads();

    if (tid < 64) {
        unsigned long long tot = 0;
        #pragma unroll
        for (int jj = 0; jj < 16; ++jj) tot += s_part[jj][seg];
        float in = (float)(tot >> 42);
        float sp = (float)((tot >> 21) & 0x1FFFFFull);
        float st = (float)(tot & 0x1FFFFFull);
        float uni = sp + st;
        float local = (uni > 0.0f) ? (2.0f * in / uni) : 1.0f;
        #pragma unroll
        for (int off = 32; off > 0; off >>= 1)
            local += __shfl_down(local, off);
        if (tid == 0) out[0] = 1.0f - local / (float)(*nc_ptr);
    }
}

extern "C" void kernel_launch(void* const* d_in, const int* in_sizes, int n_in,
                              void* d_out, int out_size, void* d_ws, size_t ws_size,
                              hipStream_t stream) {
    const float* pred   = (const float*)d_in[0];
    const float* target = (const float*)d_in[1];
    const int*   labels = (const int*)d_in[2];
    const int*   nc_ptr = (const int*)d_in[3];
    float* out = (float*)d_out;
    unsigned long long* g_part = (unsigned long long*)d_ws;  // 1 MB, fully overwritten

    const int n = in_sizes[0];

    seg_count_kernel<<<NBLK, THREADS, 0, stream>>>(
        pred, target, labels, g_part, n);
    reduce_finalize_kernel<<<1, 1024, 0, stream>>>(g_part, nc_ptr, out);
}